// Round 1
// 370.879 us; speedup vs baseline: 1.0129x; 1.0129x over previous
//
#include <hip/hip_runtime.h>

#define NBINS 256
#define NCHAN 192                         // 64*3 channels
#define HIST_BPC 8                        // blocks per channel, pass 1
#define APPLY_BPC 8                       // blocks per channel, pass 3
#define TPB 256
#define VEC_PER_CHAN (512 * 512 / 4)      // 65536 float4 per channel
#define NCOPY 16                          // bank-replicated LDS table copies (16 KiB -> 8 blocks/CU)

typedef float f4 __attribute__((ext_vector_type(4)));

// Pass 1: pure histogram. x is re-read in pass 3 (it stays LLC-resident: 201 MB < 256 MiB
// Infinity Cache). No packed intermediate -> no 50 MB write-back, block is read-bound.
// Replicated LDS histogram: lane l uses copy l>>2; atomic banks = cp + 16*(bin&1),
// ~2 lanes/bank expected on random bins (free per m136).
__global__ __launch_bounds__(TPB) void hist_kernel(const float* __restrict__ x,
                                                   int* __restrict__ partials) {
    __shared__ int lh[NBINS * NCOPY];     // 16 KiB
    const int chan = blockIdx.x / HIST_BPC;
    const int blk  = blockIdx.x % HIST_BPC;
    const int tid  = threadIdx.x;
    const int cp   = (tid & 63) >> 2;

    for (int i = tid; i < NBINS * NCOPY; i += TPB) lh[i] = 0;
    __syncthreads();

    const int vecPerBlock = VEC_PER_CHAN / HIST_BPC;  // 8192 -> 32 iters/thread
    const size_t base = (size_t)chan * VEC_PER_CHAN + (size_t)blk * vecPerBlock;
    const f4* bx = (const f4*)x + base;

    #pragma unroll 4
    for (int i = tid; i < vecPerBlock; i += TPB) {
        f4 v = bx[i];
        int a = (int)fminf(fmaxf(v.x, 0.f), 255.f);
        int b = (int)fminf(fmaxf(v.y, 0.f), 255.f);
        int c = (int)fminf(fmaxf(v.z, 0.f), 255.f);
        int d = (int)fminf(fmaxf(v.w, 0.f), 255.f);
        atomicAdd(&lh[(a << 4) + cp], 1);
        atomicAdd(&lh[(b << 4) + cp], 1);
        atomicAdd(&lh[(c << 4) + cp], 1);
        atomicAdd(&lh[(d << 4) + cp], 1);
    }
    __syncthreads();

    // reduce the 16 copies of bin `tid` (rotated: lanes tid/tid+32 share a bank -> 2-way, free)
    int s = 0;
    #pragma unroll
    for (int k = 0; k < NCOPY; ++k) s += lh[(tid << 4) + ((tid + k) & 15)];
    partials[(chan * HIST_BPC + blk) * NBINS + tid] = s;
}

// Pass 2: one block per channel computes the 256-entry LUT once (exact-int math,
// identical to the fp32 reference: all intermediates < 2^24). Removes the
// per-apply-block scan redundancy (was ~16 __syncthreads x 1536 blocks).
__global__ __launch_bounds__(TPB) void lut_kernel(const int* __restrict__ partials,
                                                  float* __restrict__ lut) {
    __shared__ int scan[NBINS];
    __shared__ int s_last_idx, s_last;
    const int chan = blockIdx.x;
    const int tid  = threadIdx.x;

    int h = 0;
    #pragma unroll
    for (int b = 0; b < HIST_BPC; ++b)
        h += partials[(chan * HIST_BPC + b) * NBINS + tid];
    scan[tid] = h;
    if (tid == 0) s_last_idx = 0;
    __syncthreads();
    if (h > 0) atomicMax(&s_last_idx, tid);

    for (int off = 1; off < NBINS; off <<= 1) {   // inclusive Hillis-Steele scan
        __syncthreads();
        int t = (tid >= off) ? scan[tid - off] : 0;
        __syncthreads();
        scan[tid] += t;
    }
    __syncthreads();
    if (tid == s_last_idx) s_last = h;            // count of last nonzero bin
    __syncthreads();

    const int total = scan[NBINS - 1];
    const int step  = (total - s_last) / 255;     // floor, nonneg

    float lutv;
    if (step == 0)      lutv = (float)tid;        // identity
    else if (tid == 0)  lutv = 0.f;               // shifted-in leading zero
    else {
        int l = (scan[tid - 1] + (step >> 1)) / step;
        lutv = (float)(l < 255 ? l : 255);
    }
    lut[chan * NBINS + tid] = lutv;
}

// Pass 3: re-read x (LLC-resident), gather through bank-replicated LDS LUT,
// nontemporal store of out (never re-read; keeps x from being evicted from LLC).
// Same-address LDS reads broadcast, so worst case ~2-way conflicts.
__global__ __launch_bounds__(TPB) void apply_kernel(const float* __restrict__ x,
                                                    float* __restrict__ out,
                                                    const float* __restrict__ lut) {
    __shared__ float slut[NBINS * NCOPY]; // 16 KiB
    const int chan = blockIdx.x / APPLY_BPC;
    const int blk  = blockIdx.x % APPLY_BPC;
    const int tid  = threadIdx.x;
    const int cp   = (tid & 63) >> 2;

    const float lv = lut[chan * NBINS + tid];
    #pragma unroll
    for (int k = 0; k < NCOPY; ++k) slut[(tid << 4) + ((tid + k) & 15)] = lv;
    __syncthreads();

    const int vecPerBlock = VEC_PER_CHAN / APPLY_BPC;  // 8192 -> 32 iters/thread
    const size_t base = (size_t)chan * VEC_PER_CHAN + (size_t)blk * vecPerBlock;
    const f4* bx = (const f4*)x + base;
    f4* bo = (f4*)out + base;

    #pragma unroll 4
    for (int i = tid; i < vecPerBlock; i += TPB) {
        f4 v = bx[i];
        int a = (int)fminf(fmaxf(v.x, 0.f), 255.f);
        int b = (int)fminf(fmaxf(v.y, 0.f), 255.f);
        int c = (int)fminf(fmaxf(v.z, 0.f), 255.f);
        int d = (int)fminf(fmaxf(v.w, 0.f), 255.f);
        f4 o;
        o.x = slut[(a << 4) + cp];
        o.y = slut[(b << 4) + cp];
        o.z = slut[(c << 4) + cp];
        o.w = slut[(d << 4) + cp];
        __builtin_nontemporal_store(o, &bo[i]);
    }
}

extern "C" void kernel_launch(void* const* d_in, const int* in_sizes, int n_in,
                              void* d_out, int out_size, void* d_ws, size_t ws_size,
                              hipStream_t stream) {
    const float* x = (const float*)d_in[0];
    // d_in[1] is `magnitude` — unused by the reference.
    float* out = (float*)d_out;

    // ws layout: [partials: 192*8*256 ints = 1.5 MiB][lut: 192*256 floats = 192 KiB]
    int* partials = (int*)d_ws;
    float* lut = (float*)((int*)d_ws + (size_t)NCHAN * HIST_BPC * NBINS);

    hist_kernel<<<NCHAN * HIST_BPC, TPB, 0, stream>>>(x, partials);
    lut_kernel<<<NCHAN, TPB, 0, stream>>>(partials, lut);
    apply_kernel<<<NCHAN * APPLY_BPC, TPB, 0, stream>>>(x, out, lut);
}

// Round 3
// 365.505 us; speedup vs baseline: 1.0278x; 1.0147x over previous
//
#include <hip/hip_runtime.h>

#define NBINS 256
#define NCHAN 192                    // 64*3 channels, one block each
#define TPB 1024                     // 16 waves; whole channel in one block
#define VEC_PER_CHAN 65536           // float4 per channel (512*512/4)
#define NCOPY 32                     // bank-private LDS replication

typedef float f4 __attribute__((ext_vector_type(4)));

// Single fused kernel: one block owns one full channel (262144 px).
// Phase A: stream x, clamp->u8, histogram into bank-replicated LDS
//          (lanes 2k,2k+1 -> copy k -> bank k always: 2 lanes/bank = free, m136).
// Phase B: block-local copy-reduce + Hillis-Steele scan -> exact-int LUT
//          (identical to the fp32 reference: all intermediates < 2^24).
// Phase C: re-read x (should be L3-resident: 192 MB < 256 MiB, nothing evicts
//          in between since out-stores are nontemporal), gather LUT, nt-store.
// No workspace, no second launch, no register-resident payload (round-2 lesson:
// 64 payload VGPRs under the 128-VGPR cap of a 16-wave block cannot fit).
__global__ __launch_bounds__(TPB) void equalize_fused(const float* __restrict__ x,
                                                      float* __restrict__ out) {
    __shared__ int   lh[NBINS * NCOPY];    // 32 KiB
    __shared__ float slut[NBINS * NCOPY];  // 32 KiB
    __shared__ int   scan[NBINS];
    __shared__ int   s_last_idx, s_last;

    const int chan = blockIdx.x;
    const int tid  = threadIdx.x;
    const int cp   = (tid & 63) >> 1;      // lanes 2k,2k+1 -> copy k (bank k)

    for (int i = tid; i < NBINS * NCOPY; i += TPB) lh[i] = 0;
    if (tid == 0) s_last_idx = 0;
    __syncthreads();

    const size_t base = (size_t)chan * VEC_PER_CHAN;
    const f4* bx = (const f4*)x + base;

    #pragma unroll 4
    for (int i = tid; i < VEC_PER_CHAN; i += TPB) {
        f4 v = bx[i];
        int a = (int)fminf(fmaxf(v.x, 0.f), 255.f);
        int b = (int)fminf(fmaxf(v.y, 0.f), 255.f);
        int c = (int)fminf(fmaxf(v.z, 0.f), 255.f);
        int d = (int)fminf(fmaxf(v.w, 0.f), 255.f);
        atomicAdd(&lh[(a << 5) + cp], 1);
        atomicAdd(&lh[(b << 5) + cp], 1);
        atomicAdd(&lh[(c << 5) + cp], 1);
        atomicAdd(&lh[(d << 5) + cp], 1);
    }
    __syncthreads();

    // reduce the 32 copies of bin `tid` (rotated -> 2-way conflicts only)
    int h = 0;
    if (tid < NBINS) {
        #pragma unroll
        for (int k = 0; k < NCOPY; ++k) h += lh[(tid << 5) + ((tid + k) & 31)];
        scan[tid] = h;
    }
    __syncthreads();
    if (tid < NBINS && h > 0) atomicMax(&s_last_idx, tid);

    for (int off = 1; off < NBINS; off <<= 1) {   // inclusive Hillis-Steele scan
        int t = 0;
        if (tid >= off && tid < NBINS) t = scan[tid - off];
        __syncthreads();
        if (tid < NBINS) scan[tid] += t;
        __syncthreads();
    }
    if (tid == s_last_idx) s_last = h;            // count of last nonzero bin
    __syncthreads();

    const int total = scan[NBINS - 1];
    const int step  = (total - s_last) / 255;     // floor, nonneg

    if (tid < NBINS) {
        float lutv;
        if (step == 0)      lutv = (float)tid;    // identity
        else if (tid == 0)  lutv = 0.f;           // shifted-in leading zero
        else {
            int l = (scan[tid - 1] + (step >> 1)) / step;
            lutv = (float)(l < 255 ? l : 255);
        }
        #pragma unroll
        for (int k = 0; k < NCOPY; ++k) slut[(tid << 5) + ((tid + k) & 31)] = lutv;
    }
    __syncthreads();

    f4* bo = (f4*)out + base;
    #pragma unroll 4
    for (int i = tid; i < VEC_PER_CHAN; i += TPB) {
        f4 v = bx[i];                              // re-read: expect L3 hit
        int a = (int)fminf(fmaxf(v.x, 0.f), 255.f);
        int b = (int)fminf(fmaxf(v.y, 0.f), 255.f);
        int c = (int)fminf(fmaxf(v.z, 0.f), 255.f);
        int d = (int)fminf(fmaxf(v.w, 0.f), 255.f);
        f4 o;
        o.x = slut[(a << 5) + cp];
        o.y = slut[(b << 5) + cp];
        o.z = slut[(c << 5) + cp];
        o.w = slut[(d << 5) + cp];
        __builtin_nontemporal_store(o, &bo[i]);
    }
}

extern "C" void kernel_launch(void* const* d_in, const int* in_sizes, int n_in,
                              void* d_out, int out_size, void* d_ws, size_t ws_size,
                              hipStream_t stream) {
    const float* x = (const float*)d_in[0];
    // d_in[1] is `magnitude` — unused by the reference.
    float* out = (float*)d_out;
    (void)d_ws; (void)ws_size;

    equalize_fused<<<NCHAN, TPB, 0, stream>>>(x, out);
}